// Round 4
// baseline (401.604 us; speedup 1.0000x reference)
//
#include <hip/hip_runtime.h>

using bf16x8 = __attribute__((ext_vector_type(8))) __bf16;
using f32x4  = __attribute__((ext_vector_type(4))) float;
using f32x16 = __attribute__((ext_vector_type(16))) float;

#define C_ 64
#define S_ 128
#define H_ 2048
#define M_ 8192

__device__ __forceinline__ unsigned short f2bf(float f) {
  unsigned u = __float_as_uint(f);
  u = u + 0x7fffu + ((u >> 16) & 1u);   // RNE
  return (unsigned short)(u >> 16);
}
__device__ __forceinline__ float bf2f(unsigned short h) {
  return __uint_as_float(((unsigned)h) << 16);
}

// async global->LDS, 16 B per lane; LDS dest = uniform base + lane*16
__device__ __forceinline__ void glds16(const unsigned short* g, unsigned short* l) {
  __builtin_amdgcn_global_load_lds(
      (const __attribute__((address_space(1))) void*)g,
      (__attribute__((address_space(3))) void*)l, 16, 0, 0);
}

// ---------------- split x into hi/lo bf16 ----------------
__global__ void k_split_x(const float* __restrict__ x,
                          unsigned short* __restrict__ xh,
                          unsigned short* __restrict__ xl) {
  int idx = blockIdx.x * 256 + threadIdx.x;
  float4 v = ((const float4*)x)[idx];
  float a[4] = {v.x, v.y, v.z, v.w};
  unsigned short h[4], l[4];
#pragma unroll
  for (int q = 0; q < 4; ++q) {
    h[q] = f2bf(a[q]);
    l[q] = f2bf(a[q] - bf2f(h[q]));
  }
  ((ushort4*)xh)[idx] = make_ushort4(h[0], h[1], h[2], h[3]);
  ((ushort4*)xl)[idx] = make_ushort4(l[0], l[1], l[2], l[3]);
}

// ------------- split + transpose W -> Wt[n][k] hi/lo -------------
__global__ void k_split_tw(const float* __restrict__ W,
                           unsigned short* __restrict__ Wth,
                           unsigned short* __restrict__ Wtl) {
  __shared__ float Ts[64][68];
  const int t = threadIdx.x;
  const int k0 = blockIdx.x * 64, n0 = blockIdx.y * 64;
#pragma unroll
  for (int p = 0; p < 4; ++p) {
    int idx = t + p * 256;
    int r = idx >> 4, c4 = (idx & 15) * 4;
    *(float4*)&Ts[r][c4] = *(const float4*)(W + (size_t)(k0 + r) * H_ + n0 + c4);
  }
  __syncthreads();
#pragma unroll
  for (int p = 0; p < 4; ++p) {
    int idx = t + p * 256;
    int rr = idx >> 4, cc = (idx & 15) * 4;   // rr = n-local, cc = k-local
    unsigned short h[4], l[4];
#pragma unroll
    for (int q = 0; q < 4; ++q) {
      float f = Ts[cc + q][rr];
      h[q] = f2bf(f);
      l[q] = f2bf(f - bf2f(h[q]));
    }
    size_t o = (size_t)(n0 + rr) * H_ + k0 + cc;
    *(ushort4*)(Wth + o) = make_ushort4(h[0], h[1], h[2], h[3]);
    *(ushort4*)(Wtl + o) = make_ushort4(l[0], l[1], l[2], l[3]);
  }
}

// ------- 3-term split-bf16 MFMA GEMM (32x32x16 core): E = A * Bt^T, bf16-pair out -------
// LDS: 128 rows x 32 ushorts (64 B), no padding; 16B groups XOR-swizzled by
// ((row>>1)&3) -> glds staging and fragment reads both conflict-free (<=2-way).
__global__ __launch_bounds__(256, 4) void k_gemm3(
    const unsigned short* __restrict__ Ah, const unsigned short* __restrict__ Al,
    const unsigned short* __restrict__ Bh, const unsigned short* __restrict__ Bl,
    unsigned short* __restrict__ Eh, unsigned short* __restrict__ El) {
  __shared__ unsigned short sAh[128 * 32], sAl[128 * 32], sBh[128 * 32], sBl[128 * 32];
  const int t = threadIdx.x;
  const int bn = blockIdx.x, bm = blockIdx.y;
  const int lane = t & 63, wid = t >> 6;
  const int wm = wid >> 1, wn = wid & 1;

  // ---- staging geometry (unchanged from 16x16 version) ----
  const int rl = lane >> 2;                    // row within 16-row chunk
  const int gg = (lane & 3) ^ ((rl >> 1) & 3); // swizzled global 16B-group
  const int c0 = wid * 2, c1 = wid * 2 + 1;
  const unsigned short* gAh0 = Ah + (size_t)(bm * 128 + c0 * 16 + rl) * H_ + gg * 8;
  const unsigned short* gAh1 = Ah + (size_t)(bm * 128 + c1 * 16 + rl) * H_ + gg * 8;
  const unsigned short* gAl0 = Al + (size_t)(bm * 128 + c0 * 16 + rl) * H_ + gg * 8;
  const unsigned short* gAl1 = Al + (size_t)(bm * 128 + c1 * 16 + rl) * H_ + gg * 8;
  const unsigned short* gBh0 = Bh + (size_t)(bn * 128 + c0 * 16 + rl) * H_ + gg * 8;
  const unsigned short* gBh1 = Bh + (size_t)(bn * 128 + c1 * 16 + rl) * H_ + gg * 8;
  const unsigned short* gBl0 = Bl + (size_t)(bn * 128 + c0 * 16 + rl) * H_ + gg * 8;
  const unsigned short* gBl1 = Bl + (size_t)(bn * 128 + c1 * 16 + rl) * H_ + gg * 8;
  unsigned short* lA0 = sAh + c0 * 512;
  unsigned short* lA1 = sAh + c1 * 512;
  unsigned short* lAl0 = sAl + c0 * 512;
  unsigned short* lAl1 = sAl + c1 * 512;
  unsigned short* lB0 = sBh + c0 * 512;
  unsigned short* lB1 = sBh + c1 * 512;
  unsigned short* lBl0 = sBl + c0 * 512;
  unsigned short* lBl1 = sBl + c1 * 512;

  // ---- 32x32x16 fragment geometry ----
  // A[m=lane&31][k = (lane>>5)*8 + j], j=0..7 (8 bf16 = 4 VGPRs)
  const int r32 = lane & 31;
  const int khalf = lane >> 5;               // 0..1
  const int swz = (r32 >> 1) & 3;            // row-XOR swizzle (tile bases are %32==0)

  f32x16 acc[2][2];
#pragma unroll
  for (int i = 0; i < 2; ++i)
#pragma unroll
    for (int j = 0; j < 2; ++j) acc[i][j] = (f32x16)0.f;

  for (int k0 = 0; k0 < H_; k0 += 32) {
    __syncthreads();
    glds16(gAh0 + k0, lA0);
    glds16(gAh1 + k0, lA1);
    glds16(gAl0 + k0, lAl0);
    glds16(gAl1 + k0, lAl1);
    glds16(gBh0 + k0, lB0);
    glds16(gBh1 + k0, lB1);
    glds16(gBl0 + k0, lBl0);
    glds16(gBl1 + k0, lBl1);
    __syncthreads();

    bf16x8 ah[2][2], al[2][2], bh[2][2], bl[2][2];   // [tile][k-half]
#pragma unroll
    for (int im = 0; im < 2; ++im) {
      const int ra = (wm * 64 + im * 32 + r32) * 32;
      const int rb = (wn * 64 + im * 32 + r32) * 32;
#pragma unroll
      for (int kh = 0; kh < 2; ++kh) {
        const int cq = (((kh * 2 + khalf) ^ swz) * 8);
        ah[im][kh] = *(const bf16x8*)&sAh[ra + cq];
        al[im][kh] = *(const bf16x8*)&sAl[ra + cq];
        bh[im][kh] = *(const bf16x8*)&sBh[rb + cq];
        bl[im][kh] = *(const bf16x8*)&sBl[rb + cq];
      }
    }
#pragma unroll
    for (int im = 0; im < 2; ++im)
#pragma unroll
      for (int jn = 0; jn < 2; ++jn)
#pragma unroll
        for (int kh = 0; kh < 2; ++kh) {
          acc[im][jn] = __builtin_amdgcn_mfma_f32_32x32x16_bf16(ah[im][kh], bh[jn][kh], acc[im][jn], 0, 0, 0);
          acc[im][jn] = __builtin_amdgcn_mfma_f32_32x32x16_bf16(ah[im][kh], bl[jn][kh], acc[im][jn], 0, 0, 0);
          acc[im][jn] = __builtin_amdgcn_mfma_f32_32x32x16_bf16(al[im][kh], bh[jn][kh], acc[im][jn], 0, 0, 0);
        }
  }

  // C/D (32x32): col = lane&31, row = (reg&3) + 8*(reg>>2) + 4*(lane>>5)
#pragma unroll
  for (int im = 0; im < 2; ++im)
#pragma unroll
    for (int jn = 0; jn < 2; ++jn) {
      const int col = bn * 128 + wn * 64 + jn * 32 + r32;
#pragma unroll
      for (int reg = 0; reg < 16; ++reg) {
        const int row = bm * 128 + wm * 64 + im * 32 + (reg & 3) + 8 * (reg >> 2) + 4 * khalf;
        float v = acc[im][jn][reg];
        unsigned short hh = f2bf(v);
        unsigned short ll = f2bf(v - bf2f(hh));
        Eh[(size_t)row * H_ + col] = hh;
        El[(size_t)row * H_ + col] = ll;
      }
    }
}

// ---- MFMA Gram: G[c] += Eh*Eh^T + Eh*El^T + El*Eh^T over a 256-wide K chunk ----
__global__ __launch_bounds__(256, 4) void k_gram_mfma(
    const unsigned short* __restrict__ Eh, const unsigned short* __restrict__ El,
    float* __restrict__ G) {
  __shared__ unsigned short sH[128 * 32], sL[128 * 32];
  const int t = threadIdx.x;
  const int kc = blockIdx.x;   // 0..7, K chunk of 256
  const int cc = blockIdx.y;   // capsule
  const int lane = t & 63, wid = t >> 6;
  const int wm = wid >> 1, wn = wid & 1;
  const int l16 = lane & 15, quad = lane >> 4;

  const int rl = lane >> 2;
  const int gg = (lane & 3) ^ ((rl >> 1) & 3);
  const int c0 = wid * 2, c1 = c0 + 1;
  const size_t kbase = (size_t)kc * 256 + gg * 8;
  const unsigned short* gH0 = Eh + (size_t)(cc * 128 + c0 * 16 + rl) * H_ + kbase;
  const unsigned short* gH1 = Eh + (size_t)(cc * 128 + c1 * 16 + rl) * H_ + kbase;
  const unsigned short* gL0 = El + (size_t)(cc * 128 + c0 * 16 + rl) * H_ + kbase;
  const unsigned short* gL1 = El + (size_t)(cc * 128 + c1 * 16 + rl) * H_ + kbase;
  unsigned short* lH0 = sH + c0 * 512;
  unsigned short* lH1 = sH + c1 * 512;
  unsigned short* lL0 = sL + c0 * 512;
  unsigned short* lL1 = sL + c1 * 512;

  const int swz = ((l16 >> 1) & 3);
  const int colq = ((quad ^ swz) * 8);

  f32x4 acc[4][4];
#pragma unroll
  for (int i = 0; i < 4; ++i)
#pragma unroll
    for (int j = 0; j < 4; ++j) acc[i][j] = (f32x4)0.f;

  for (int k0 = 0; k0 < 256; k0 += 32) {
    __syncthreads();
    glds16(gH0 + k0, lH0);
    glds16(gH1 + k0, lH1);
    glds16(gL0 + k0, lL0);
    glds16(gL1 + k0, lL1);
    __syncthreads();

    bf16x8 ah[4], al[4], bh[4], bl[4];
#pragma unroll
    for (int i = 0; i < 4; ++i) {
      const int ra = (wm * 64 + i * 16 + l16) * 32;
      const int rb = (wn * 64 + i * 16 + l16) * 32;
      ah[i] = *(const bf16x8*)&sH[ra + colq];
      al[i] = *(const bf16x8*)&sL[ra + colq];
      bh[i] = *(const bf16x8*)&sH[rb + colq];
      bl[i] = *(const bf16x8*)&sL[rb + colq];
    }
#pragma unroll
    for (int i = 0; i < 4; ++i)
#pragma unroll
      for (int j = 0; j < 4; ++j) {
        acc[i][j] = __builtin_amdgcn_mfma_f32_16x16x32_bf16(ah[i], bh[j], acc[i][j], 0, 0, 0);
        acc[i][j] = __builtin_amdgcn_mfma_f32_16x16x32_bf16(ah[i], bl[j], acc[i][j], 0, 0, 0);
        acc[i][j] = __builtin_amdgcn_mfma_f32_16x16x32_bf16(al[i], bh[j], acc[i][j], 0, 0, 0);
      }
  }

  float* Gc = G + (size_t)cc * S_ * S_;
#pragma unroll
  for (int i = 0; i < 4; ++i) {
    const int row0 = wm * 64 + i * 16 + quad * 4;
#pragma unroll
    for (int j = 0; j < 4; ++j) {
      const int col = wn * 64 + j * 16 + l16;
#pragma unroll
      for (int r = 0; r < 4; ++r)
        atomicAdd(&Gc[(row0 + r) * S_ + col], acc[i][j][r]);
    }
  }
}

// ---------- per-capsule routing iterations on G only ----------
__global__ void k_iter(const float* __restrict__ G, float* __restrict__ wv) {
  const int c = blockIdx.x;
  const int s = threadIdx.x;   // 128 threads
  __shared__ float dsh[128];
  __shared__ float red[128];
  const float* Gc = G + (size_t)c * S_ * S_;
  float b = 0.f;
  for (int it = 0; it < 3; ++it) {
    red[s] = b; __syncthreads();
    for (int off = 64; off > 0; off >>= 1) {
      if (s < off) red[s] = fmaxf(red[s], red[s + off]);
      __syncthreads();
    }
    float mx = red[0]; __syncthreads();
    float ev = expf(b - mx);
    red[s] = ev; __syncthreads();
    for (int off = 64; off > 0; off >>= 1) {
      if (s < off) red[s] = red[s] + red[s + off];
      __syncthreads();
    }
    float Z = red[0]; __syncthreads();
    float d = ev / Z;
    dsh[s] = d; __syncthreads();
    float y = 0.f;
#pragma unroll 8
    for (int j = 0; j < S_; ++j) y = fmaf(Gc[j * S_ + s], dsh[j], y);
    red[s] = d * y; __syncthreads();
    for (int off = 64; off > 0; off >>= 1) {
      if (s < off) red[s] = red[s] + red[s + off];
      __syncthreads();
    }
    float sq = red[0]; __syncthreads();
    float coeff = sq / (1.f + sq) / sqrtf(sq + 1e-9f);
    if (it == 2) wv[c * S_ + s] = coeff * d;
    else b += coeff * y;
  }
}

// ---------- out[c,h] = sum_s wv[c,s] * (Eh+El)[c,s,h], 2 h per thread ----------
__global__ void k_out(const unsigned short* __restrict__ Eh,
                      const unsigned short* __restrict__ El,
                      const float* __restrict__ wv, float* __restrict__ out) {
  const int c = blockIdx.y;
  const int h2 = blockIdx.x * 256 + threadIdx.x;   // dword index, grid.x = 4
  __shared__ float wsh[128];
  if (threadIdx.x < 128) wsh[threadIdx.x] = wv[c * S_ + threadIdx.x];
  __syncthreads();
  const unsigned* Ph = (const unsigned*)(Eh + (size_t)c * S_ * H_) + h2;
  const unsigned* Pl = (const unsigned*)(El + (size_t)c * S_ * H_) + h2;
  float a0 = 0.f, a1 = 0.f;
#pragma unroll 8
  for (int s = 0; s < S_; ++s) {
    unsigned uh = Ph[(size_t)s * (H_ / 2)];
    unsigned ul = Pl[(size_t)s * (H_ / 2)];
    a0 = fmaf(wsh[s], bf2f((unsigned short)uh) + bf2f((unsigned short)ul), a0);
    a1 = fmaf(wsh[s], bf2f((unsigned short)(uh >> 16)) + bf2f((unsigned short)(ul >> 16)), a1);
  }
  ((float2*)(out + (size_t)c * H_))[h2] = make_float2(a0, a1);
}

extern "C" void kernel_launch(void* const* d_in, const int* in_sizes, int n_in,
                              void* d_out, int out_size, void* d_ws, size_t ws_size,
                              hipStream_t stream) {
  (void)in_sizes; (void)n_in; (void)out_size; (void)ws_size;
  const float* x = (const float*)d_in[0];
  const float* W = (const float*)d_in[1];
  float* out = (float*)d_out;
  char* ws = (char*)d_ws;

  unsigned short* xh  = (unsigned short*)(ws);                 // 32 MiB
  unsigned short* xl  = (unsigned short*)(ws + 33554432);      // 32 MiB
  unsigned short* Wth = (unsigned short*)(ws + 67108864);      // 8 MiB
  unsigned short* Wtl = (unsigned short*)(ws + 75497472);      // 8 MiB
  unsigned short* Eh  = (unsigned short*)(ws + 83886080);      // 32 MiB
  unsigned short* El  = (unsigned short*)(ws + 117440512);     // 32 MiB
  float*          G   = (float*)(ws + 150994944);              // 4 MiB
  float*          wv  = (float*)(ws + 155189248);              // 32 KiB

  hipMemsetAsync(G, 0, (size_t)C_ * S_ * S_ * sizeof(float), stream);
  k_split_x<<<dim3(16384), 256, 0, stream>>>(x, xh, xl);
  k_split_tw<<<dim3(32, 32), 256, 0, stream>>>(W, Wth, Wtl);
  k_gemm3<<<dim3(16, 64), 256, 0, stream>>>(xh, xl, Wth, Wtl, Eh, El);
  k_gram_mfma<<<dim3(8, 64), 256, 0, stream>>>(Eh, El, G);
  k_iter<<<dim3(64), 128, 0, stream>>>(G, wv);
  k_out<<<dim3(4, 64), 256, 0, stream>>>(Eh, El, wv, out);
}

// Round 5
// 380.506 us; speedup vs baseline: 1.0554x; 1.0554x over previous
//
#include <hip/hip_runtime.h>

using bf16x8 = __attribute__((ext_vector_type(8))) __bf16;
using f32x4  = __attribute__((ext_vector_type(4))) float;

#define C_ 64
#define S_ 128
#define H_ 2048
#define M_ 8192

__device__ __forceinline__ unsigned short f2bf(float f) {
  unsigned u = __float_as_uint(f);
  u = u + 0x7fffu + ((u >> 16) & 1u);   // RNE
  return (unsigned short)(u >> 16);
}
__device__ __forceinline__ float bf2f(unsigned short h) {
  return __uint_as_float(((unsigned)h) << 16);
}

// async global->LDS, 16 B per lane; LDS dest = uniform base + lane*16
__device__ __forceinline__ void glds16(const unsigned short* g, unsigned short* l) {
  __builtin_amdgcn_global_load_lds(
      (const __attribute__((address_space(1))) void*)g,
      (__attribute__((address_space(3))) void*)l, 16, 0, 0);
}

// ---- fused: split x (blocks 0..16383) | split+transpose W (16384..17407) | zero G ----
__global__ void k_split_all(const float* __restrict__ x,
                            unsigned short* __restrict__ xh,
                            unsigned short* __restrict__ xl,
                            const float* __restrict__ W,
                            unsigned short* __restrict__ Wth,
                            unsigned short* __restrict__ Wtl,
                            float* __restrict__ G) {
  __shared__ float Ts[64][68];
  const int b = blockIdx.x;
  const int t = threadIdx.x;
  if (b < 16384) {
    int idx = b * 256 + t;
    float4 v = ((const float4*)x)[idx];
    float a[4] = {v.x, v.y, v.z, v.w};
    unsigned short h[4], l[4];
#pragma unroll
    for (int q = 0; q < 4; ++q) {
      h[q] = f2bf(a[q]);
      l[q] = f2bf(a[q] - bf2f(h[q]));
    }
    ((ushort4*)xh)[idx] = make_ushort4(h[0], h[1], h[2], h[3]);
    ((ushort4*)xl)[idx] = make_ushort4(l[0], l[1], l[2], l[3]);
  } else if (b < 17408) {
    const int bb = b - 16384;
    const int k0 = (bb & 31) * 64, n0 = (bb >> 5) * 64;
#pragma unroll
    for (int p = 0; p < 4; ++p) {
      int idx = t + p * 256;
      int r = idx >> 4, c4 = (idx & 15) * 4;
      *(float4*)&Ts[r][c4] = *(const float4*)(W + (size_t)(k0 + r) * H_ + n0 + c4);
    }
    __syncthreads();
#pragma unroll
    for (int p = 0; p < 4; ++p) {
      int idx = t + p * 256;
      int rr = idx >> 4, cc = (idx & 15) * 4;   // rr = n-local, cc = k-local
      unsigned short h[4], l[4];
#pragma unroll
      for (int q = 0; q < 4; ++q) {
        float f = Ts[cc + q][rr];
        h[q] = f2bf(f);
        l[q] = f2bf(f - bf2f(h[q]));
      }
      size_t o = (size_t)(n0 + rr) * H_ + k0 + cc;
      *(ushort4*)(Wth + o) = make_ushort4(h[0], h[1], h[2], h[3]);
      *(ushort4*)(Wtl + o) = make_ushort4(l[0], l[1], l[2], l[3]);
    }
  } else {
    const int bb = b - 17408;   // 1024 blocks * 256 threads * 16 B = 4 MiB
    ((float4*)G)[bb * 256 + t] = (float4){0.f, 0.f, 0.f, 0.f};
  }
}

// ------- 3-term split-bf16 MFMA GEMM (16x16x32 core): E = A * Bt^T, bf16-pair out -------
// LDS: 128 rows x 32 ushorts (64 B), no padding; 16B groups XOR-swizzled by
// ((row>>1)&3) -> glds staging and fragment reads both conflict-free (measured R2: 0).
__global__ __launch_bounds__(256, 4) void k_gemm3(
    const unsigned short* __restrict__ Ah, const unsigned short* __restrict__ Al,
    const unsigned short* __restrict__ Bh, const unsigned short* __restrict__ Bl,
    unsigned short* __restrict__ Eh, unsigned short* __restrict__ El) {
  __shared__ unsigned short sAh[128 * 32], sAl[128 * 32], sBh[128 * 32], sBl[128 * 32];
  const int t = threadIdx.x;
  const int bn = blockIdx.x, bm = blockIdx.y;
  const int lane = t & 63, wid = t >> 6;
  const int wm = wid >> 1, wn = wid & 1;
  const int l16 = lane & 15, quad = lane >> 4;

  const int rl = lane >> 2;                    // row within 16-row chunk
  const int gg = (lane & 3) ^ ((rl >> 1) & 3); // swizzled global 16B-group
  const int c0 = wid * 2, c1 = wid * 2 + 1;
  const unsigned short* gAh0 = Ah + (size_t)(bm * 128 + c0 * 16 + rl) * H_ + gg * 8;
  const unsigned short* gAh1 = Ah + (size_t)(bm * 128 + c1 * 16 + rl) * H_ + gg * 8;
  const unsigned short* gAl0 = Al + (size_t)(bm * 128 + c0 * 16 + rl) * H_ + gg * 8;
  const unsigned short* gAl1 = Al + (size_t)(bm * 128 + c1 * 16 + rl) * H_ + gg * 8;
  const unsigned short* gBh0 = Bh + (size_t)(bn * 128 + c0 * 16 + rl) * H_ + gg * 8;
  const unsigned short* gBh1 = Bh + (size_t)(bn * 128 + c1 * 16 + rl) * H_ + gg * 8;
  const unsigned short* gBl0 = Bl + (size_t)(bn * 128 + c0 * 16 + rl) * H_ + gg * 8;
  const unsigned short* gBl1 = Bl + (size_t)(bn * 128 + c1 * 16 + rl) * H_ + gg * 8;
  unsigned short* lA0 = sAh + c0 * 512;  // chunk = 16 rows * 32 ushorts = 1 KiB
  unsigned short* lA1 = sAh + c1 * 512;
  unsigned short* lAl0 = sAl + c0 * 512;
  unsigned short* lAl1 = sAl + c1 * 512;
  unsigned short* lB0 = sBh + c0 * 512;
  unsigned short* lB1 = sBh + c1 * 512;
  unsigned short* lBl0 = sBl + c0 * 512;
  unsigned short* lBl1 = sBl + c1 * 512;

  const int swz = ((l16 >> 1) & 3);
  const int colq = ((quad ^ swz) * 8);

  f32x4 acc[4][4];
#pragma unroll
  for (int i = 0; i < 4; ++i)
#pragma unroll
    for (int j = 0; j < 4; ++j) acc[i][j] = (f32x4)0.f;

  for (int k0 = 0; k0 < H_; k0 += 32) {
    __syncthreads();
    glds16(gAh0 + k0, lA0);
    glds16(gAh1 + k0, lA1);
    glds16(gAl0 + k0, lAl0);
    glds16(gAl1 + k0, lAl1);
    glds16(gBh0 + k0, lB0);
    glds16(gBh1 + k0, lB1);
    glds16(gBl0 + k0, lBl0);
    glds16(gBl1 + k0, lBl1);
    __syncthreads();

    bf16x8 ah[4], al[4], bh[4], bl[4];
#pragma unroll
    for (int i = 0; i < 4; ++i) {
      const int ra = (wm * 64 + i * 16 + l16) * 32;
      const int rb = (wn * 64 + i * 16 + l16) * 32;
      ah[i] = *(const bf16x8*)&sAh[ra + colq];
      al[i] = *(const bf16x8*)&sAl[ra + colq];
      bh[i] = *(const bf16x8*)&sBh[rb + colq];
      bl[i] = *(const bf16x8*)&sBl[rb + colq];
    }
#pragma unroll
    for (int i = 0; i < 4; ++i)
#pragma unroll
      for (int j = 0; j < 4; ++j) {
        acc[i][j] = __builtin_amdgcn_mfma_f32_16x16x32_bf16(ah[i], bh[j], acc[i][j], 0, 0, 0);
        acc[i][j] = __builtin_amdgcn_mfma_f32_16x16x32_bf16(ah[i], bl[j], acc[i][j], 0, 0, 0);
        acc[i][j] = __builtin_amdgcn_mfma_f32_16x16x32_bf16(al[i], bh[j], acc[i][j], 0, 0, 0);
      }
  }

#pragma unroll
  for (int i = 0; i < 4; ++i) {
    const int row0 = bm * 128 + wm * 64 + i * 16 + quad * 4;
#pragma unroll
    for (int j = 0; j < 4; ++j) {
      const int col = bn * 128 + wn * 64 + j * 16 + l16;
#pragma unroll
      for (int r = 0; r < 4; ++r) {
        float v = acc[i][j][r];
        unsigned short hh = f2bf(v);
        unsigned short ll = f2bf(v - bf2f(hh));
        Eh[(size_t)(row0 + r) * H_ + col] = hh;
        El[(size_t)(row0 + r) * H_ + col] = ll;
      }
    }
  }
}

// ---- MFMA Gram: G[c] += Eh*Eh^T + Eh*El^T + El*Eh^T over a 256-wide K chunk ----
__global__ __launch_bounds__(256, 4) void k_gram_mfma(
    const unsigned short* __restrict__ Eh, const unsigned short* __restrict__ El,
    float* __restrict__ G) {
  __shared__ unsigned short sH[128 * 32], sL[128 * 32];
  const int t = threadIdx.x;
  const int kc = blockIdx.x;   // 0..7, K chunk of 256
  const int cc = blockIdx.y;   // capsule
  const int lane = t & 63, wid = t >> 6;
  const int wm = wid >> 1, wn = wid & 1;
  const int l16 = lane & 15, quad = lane >> 4;

  const int rl = lane >> 2;
  const int gg = (lane & 3) ^ ((rl >> 1) & 3);
  const int c0 = wid * 2, c1 = c0 + 1;
  const size_t kbase = (size_t)kc * 256 + gg * 8;
  const unsigned short* gH0 = Eh + (size_t)(cc * 128 + c0 * 16 + rl) * H_ + kbase;
  const unsigned short* gH1 = Eh + (size_t)(cc * 128 + c1 * 16 + rl) * H_ + kbase;
  const unsigned short* gL0 = El + (size_t)(cc * 128 + c0 * 16 + rl) * H_ + kbase;
  const unsigned short* gL1 = El + (size_t)(cc * 128 + c1 * 16 + rl) * H_ + kbase;
  unsigned short* lH0 = sH + c0 * 512;
  unsigned short* lH1 = sH + c1 * 512;
  unsigned short* lL0 = sL + c0 * 512;
  unsigned short* lL1 = sL + c1 * 512;

  const int swz = ((l16 >> 1) & 3);
  const int colq = ((quad ^ swz) * 8);

  f32x4 acc[4][4];
#pragma unroll
  for (int i = 0; i < 4; ++i)
#pragma unroll
    for (int j = 0; j < 4; ++j) acc[i][j] = (f32x4)0.f;

  for (int k0 = 0; k0 < 256; k0 += 32) {
    __syncthreads();
    glds16(gH0 + k0, lH0);
    glds16(gH1 + k0, lH1);
    glds16(gL0 + k0, lL0);
    glds16(gL1 + k0, lL1);
    __syncthreads();

    bf16x8 ah[4], al[4], bh[4], bl[4];
#pragma unroll
    for (int i = 0; i < 4; ++i) {
      const int ra = (wm * 64 + i * 16 + l16) * 32;
      const int rb = (wn * 64 + i * 16 + l16) * 32;
      ah[i] = *(const bf16x8*)&sH[ra + colq];
      al[i] = *(const bf16x8*)&sL[ra + colq];
      bh[i] = *(const bf16x8*)&sH[rb + colq];
      bl[i] = *(const bf16x8*)&sL[rb + colq];
    }
#pragma unroll
    for (int i = 0; i < 4; ++i)
#pragma unroll
      for (int j = 0; j < 4; ++j) {
        acc[i][j] = __builtin_amdgcn_mfma_f32_16x16x32_bf16(ah[i], bh[j], acc[i][j], 0, 0, 0);
        acc[i][j] = __builtin_amdgcn_mfma_f32_16x16x32_bf16(ah[i], bl[j], acc[i][j], 0, 0, 0);
        acc[i][j] = __builtin_amdgcn_mfma_f32_16x16x32_bf16(al[i], bh[j], acc[i][j], 0, 0, 0);
      }
  }

  float* Gc = G + (size_t)cc * S_ * S_;
#pragma unroll
  for (int i = 0; i < 4; ++i) {
    const int row0 = wm * 64 + i * 16 + quad * 4;
#pragma unroll
    for (int j = 0; j < 4; ++j) {
      const int col = wn * 64 + j * 16 + l16;
#pragma unroll
      for (int r = 0; r < 4; ++r)
        atomicAdd(&Gc[(row0 + r) * S_ + col], acc[i][j][r]);
    }
  }
}

// ---- fused routing + projection: each block redoes its capsule's routing ----
// (64 KB G_c read x3 per block; redundant but tiny. Barriers are block-uniform:
//  s = tid & 127 -> threads tid and tid+128 compute identical values.)
__global__ void k_out2(const unsigned short* __restrict__ Eh,
                       const unsigned short* __restrict__ El,
                       const float* __restrict__ G, float* __restrict__ out) {
  const int c = blockIdx.y;
  const int s = threadIdx.x & 127;
  __shared__ float dsh[128];
  __shared__ float red[128];
  __shared__ float wsh[128];
  const float* Gc = G + (size_t)c * S_ * S_;
  float b = 0.f;
  for (int it = 0; it < 3; ++it) {
    red[s] = b; __syncthreads();
    for (int off = 64; off > 0; off >>= 1) {
      if (s < off) red[s] = fmaxf(red[s], red[s + off]);
      __syncthreads();
    }
    float mx = red[0]; __syncthreads();
    float ev = expf(b - mx);
    red[s] = ev; __syncthreads();
    for (int off = 64; off > 0; off >>= 1) {
      if (s < off) red[s] = red[s] + red[s + off];
      __syncthreads();
    }
    float Z = red[0]; __syncthreads();
    float d = ev / Z;
    dsh[s] = d; __syncthreads();
    float y = 0.f;   // (G d)_s via symmetric-column reads
#pragma unroll 8
    for (int j = 0; j < S_; ++j) y = fmaf(Gc[j * S_ + s], dsh[j], y);
    red[s] = d * y; __syncthreads();
    for (int off = 64; off > 0; off >>= 1) {
      if (s < off) red[s] = red[s] + red[s + off];
      __syncthreads();
    }
    float sq = red[0]; __syncthreads();
    float coeff = sq / (1.f + sq) / sqrtf(sq + 1e-9f);
    if (it == 2) wsh[s] = coeff * d;
    else b += coeff * y;
  }
  __syncthreads();

  // projection: out[c,h] = sum_s wsh[s] * (Eh+El)[c,s,h], 2 h per thread
  const int h2 = blockIdx.x * 256 + threadIdx.x;   // dword index, grid.x = 4
  const unsigned* Ph = (const unsigned*)(Eh + (size_t)c * S_ * H_) + h2;
  const unsigned* Pl = (const unsigned*)(El + (size_t)c * S_ * H_) + h2;
  float a0 = 0.f, a1 = 0.f;
#pragma unroll 8
  for (int ss = 0; ss < S_; ++ss) {
    unsigned uh = Ph[(size_t)ss * (H_ / 2)];
    unsigned ul = Pl[(size_t)ss * (H_ / 2)];
    a0 = fmaf(wsh[ss], bf2f((unsigned short)uh) + bf2f((unsigned short)ul), a0);
    a1 = fmaf(wsh[ss], bf2f((unsigned short)(uh >> 16)) + bf2f((unsigned short)(ul >> 16)), a1);
  }
  ((float2*)(out + (size_t)c * H_))[h2] = make_float2(a0, a1);
}

extern "C" void kernel_launch(void* const* d_in, const int* in_sizes, int n_in,
                              void* d_out, int out_size, void* d_ws, size_t ws_size,
                              hipStream_t stream) {
  (void)in_sizes; (void)n_in; (void)out_size; (void)ws_size;
  const float* x = (const float*)d_in[0];
  const float* W = (const float*)d_in[1];
  float* out = (float*)d_out;
  char* ws = (char*)d_ws;

  unsigned short* xh  = (unsigned short*)(ws);                 // 32 MiB
  unsigned short* xl  = (unsigned short*)(ws + 33554432);      // 32 MiB
  unsigned short* Wth = (unsigned short*)(ws + 67108864);      // 8 MiB
  unsigned short* Wtl = (unsigned short*)(ws + 75497472);      // 8 MiB
  unsigned short* Eh  = (unsigned short*)(ws + 83886080);      // 32 MiB
  unsigned short* El  = (unsigned short*)(ws + 117440512);     // 32 MiB
  float*          G   = (float*)(ws + 150994944);              // 4 MiB

  k_split_all<<<dim3(18432), 256, 0, stream>>>(x, xh, xl, W, Wth, Wtl, G);
  k_gemm3<<<dim3(16, 64), 256, 0, stream>>>(xh, xl, Wth, Wtl, Eh, El);
  k_gram_mfma<<<dim3(8, 64), 256, 0, stream>>>(Eh, El, G);
  k_out2<<<dim3(4, 64), 256, 0, stream>>>(Eh, El, G, out);
}